// Round 13
// baseline (576.940 us; speedup 1.0000x reference)
//
#include <hip/hip_runtime.h>
#include <cstdint>

// Problem geometry (fixed by the reference)
#define D_IN   4096
#define D_OUT  4096
#define MTOT   16384      // B*S = 8*2048
#define SCALING 2.0f

// GEMM tiling: 256x256 tile, BK=64, 8 waves (2M x 4N), TWO single-barrier phases
#define BM 256
#define BN 256
#define BK 64
#define KT (D_IN / BK)    // 64 K-tiles

typedef float  f32x4  __attribute__((ext_vector_type(4)));
typedef __bf16 bf16x8 __attribute__((ext_vector_type(8)));
typedef unsigned short ushort8 __attribute__((ext_vector_type(8)));
typedef int    int4v  __attribute__((ext_vector_type(4)));
typedef float  float4v __attribute__((ext_vector_type(4)));

// round-to-nearest-even f32 -> bf16
__device__ __forceinline__ unsigned short f2bf(float f) {
  union { float f; unsigned u; } v; v.f = f;
  unsigned r = v.u + 0x7FFF + ((v.u >> 16) & 1);
  return (unsigned short)(r >> 16);
}

// async global->LDS, 16B per lane (wave-uniform base + lane*16 on LDS side)
#define ASYNC16(g, l)                                                        \
  __builtin_amdgcn_global_load_lds(                                          \
      (const __attribute__((address_space(1))) unsigned int*)(g),            \
      (__attribute__((address_space(3))) unsigned int*)(l), 16, 0, 0)

#define BAR    __builtin_amdgcn_s_barrier()
#define VMW(n) asm volatile("s_waitcnt vmcnt(" #n ")" ::: "memory")

// ---------------------------------------------------------------- prep: x -> bf16
__global__ __launch_bounds__(256) void prep_x_kernel(const float* __restrict__ x,
                                                     unsigned short* __restrict__ xbf) {
  int i = (blockIdx.x * 256 + threadIdx.x) * 8;
  float4v lo = *(const float4v*)(x + i);
  float4v hi = *(const float4v*)(x + i + 4);
  ushort8 o;
  o[0] = f2bf(lo[0]); o[1] = f2bf(lo[1]); o[2] = f2bf(lo[2]); o[3] = f2bf(lo[3]);
  o[4] = f2bf(hi[0]); o[5] = f2bf(hi[1]); o[6] = f2bf(hi[2]); o[7] = f2bf(hi[3]);
  *(ushort8*)(xbf + i) = o;
}

// ------------------------------------------- prep: W_eff = dequant(codes)+2*delta
__global__ __launch_bounds__(256) void prep_w_kernel(const int* __restrict__ codes,
                                                     const float* __restrict__ scales,
                                                     const float* __restrict__ delta,
                                                     unsigned short* __restrict__ weff) {
  int i = (blockIdx.x * 256 + threadIdx.x) * 8;   // 8 consecutive elems, same group
  int row = i >> 12;          // / D_IN
  int col = i & (D_IN - 1);
  float s = scales[(row << 6) + (col >> 6)];      // 64 groups per row
  int4v   c0 = *(const int4v*)(codes + i);
  int4v   c1 = *(const int4v*)(codes + i + 4);
  float4v d0 = *(const float4v*)(delta + i);
  float4v d1 = *(const float4v*)(delta + i + 4);
  ushort8 o;
  o[0] = f2bf((float)(c0[0] - 8) * s + SCALING * d0[0]);
  o[1] = f2bf((float)(c0[1] - 8) * s + SCALING * d0[1]);
  o[2] = f2bf((float)(c0[2] - 8) * s + SCALING * d0[2]);
  o[3] = f2bf((float)(c0[3] - 8) * s + SCALING * d0[3]);
  o[4] = f2bf((float)(c1[0] - 8) * s + SCALING * d1[0]);
  o[5] = f2bf((float)(c1[1] - 8) * s + SCALING * d1[1]);
  o[6] = f2bf((float)(c1[2] - 8) * s + SCALING * d1[2]);
  o[7] = f2bf((float)(c1[3] - 8) * s + SCALING * d1[3]);
  *(ushort8*)(weff + i) = o;
}

// ---------------------------------------------------------------- main GEMM
// C[M][N] = Xbf[M][K] * Weff[N][K]^T + bias
// 256x256, BK=64, 512 thr (8 waves: wr=wid>>2, wc=wid&3).
// TWO single-barrier phases per K-tile (4 -> 2 barriers):
//   Ph0: stage B(g+1)->bufB^1 | vmcnt(4) | BAR | rd A0(8)+B0(4)+B1(4),
//        MM16(A0,B0)+MM16(A0,B1)                     [32 MFMA]
//   Ph1: stage A(g+1)->bufA^1 | BAR | rd A1(8),
//        MM16(A1,B0)+MM16(A1,B1)                     [32 MFMA]
// WAR audit (a STAGE at phase-top races only phase p-1 readers, 1 barrier back):
//   Ph0 stages bufB^1 : g-1 Ph1 reads bufA^1.A1 only      -> disjoint, safe
//   Ph1 stages bufA^1 : g   Ph0 reads bufA.A0 + bufB.*    -> disjoint, safe
//   (2-barrier-back readers of the same slots are lgkm-drained before they
//    crossed the intervening barrier.)
// vmcnt invariant (per-thread, steady state): entering Ph0, outstanding =
// [B(g)x4, A(g)x4]; stage B(g+1) -> 12; vmcnt(4) drains B(g)+A(g) — exactly
// what tile g reads — leaving B(g+1)x4 in flight (never 0 mid-loop).
// A(g)'s in-flight window = 1 phase (~1300cyc > ~900cyc HBM) — no stall.
// Bigger MFMA clusters/phase (32/wave) hide the read bursts that the 4-phase
// version exposed (r12 analysis: phase time = its own CU-wide LDS burst).
// LDS: bufA[2] slots{A0,A1} + bufB[2] slots{B0,B1}, each slot [128][64] bf16,
// XOR-swizzled byte ^= ((row&7)<<4): inverse-swizzled source + swizzled read.
// Loop unrolled x2 so buf is a LITERAL (immediate-offset folding).

// stage BOTH halves of a tile's A (slots 0,1 of lds[buf_]) — 4 loads/thread
#define STAGE_A(buf_, kt_) do {                                              \
    char* d_ = &lds[buf_][0][0] + tid * 16;                                  \
    const unsigned short* s_ = gA + (size_t)(kt_) * 64;                      \
    ASYNC16(s_, d_);                                                         \
    ASYNC16(s_ +  64 * D_IN, d_ + 8192);                                     \
    ASYNC16(s_ + 128 * D_IN, d_ + 16384);                                    \
    ASYNC16(s_ + 192 * D_IN, d_ + 24576);                                    \
  } while (0)

// stage BOTH halves of a tile's B (slots 2,3 of lds[buf_]) — 4 loads/thread
#define STAGE_B(buf_, kt_) do {                                              \
    char* d_ = &lds[buf_][2][0] + tid * 16;                                  \
    const unsigned short* s_ = gB + (size_t)(kt_) * 64;                      \
    ASYNC16(s_, d_);                                                         \
    ASYNC16(s_ +  64 * D_IN, d_ + 8192);                                     \
    ASYNC16(s_ + 128 * D_IN, d_ + 16384);                                    \
    ASYNC16(s_ + 192 * D_IN, d_ + 24576);                                    \
  } while (0)

// read A-half h_ (4 m-frags, rows h*64..h*64+63 of wave's panel) -> A[4][2]
#define RD_A(buf_, h_) do {                                                  \
    _Pragma("unroll")                                                        \
    for (int m2 = 0; m2 < 4; ++m2) {                                         \
      const char* p_ = &lds[buf_][wr][0] + ((h_)*4 + m2) * 2048 + rowb;      \
      A[m2][0] = *(const bf16x8*)(p_ + koff0);                               \
      A[m2][1] = *(const bf16x8*)(p_ + koff1);                               \
    } } while (0)

// read B-half h_ (2 n-frags) of the wave's 64-col B panel
#define RD_B(buf_, h_, dst_) do {                                            \
    _Pragma("unroll")                                                        \
    for (int n2 = 0; n2 < 2; ++n2) {                                         \
      const char* p_ = &lds[buf_][2 + (wc >> 1)][0] + (wc & 1) * 8192 +      \
                       (h_) * 4096 + n2 * 2048 + rowb;                       \
      dst_[n2][0] = *(const bf16x8*)(p_ + koff0);                            \
      dst_[n2][1] = *(const bf16x8*)(p_ + koff1);                            \
    } } while (0)

// 16 MFMA: A-half (acc rows mh*4..+3) x B-half (acc cols nh*2..+1), K=64
#define MM16(bfr_, mh_, nh_) do {                                            \
    __builtin_amdgcn_s_setprio(1);                                           \
    _Pragma("unroll")                                                        \
    for (int m2 = 0; m2 < 4; ++m2) {                                         \
      _Pragma("unroll")                                                      \
      for (int n2 = 0; n2 < 2; ++n2) {                                       \
        acc[(mh_)*4 + m2][(nh_)*2 + n2] = __builtin_amdgcn_mfma_f32_16x16x32_bf16( \
            A[m2][0], bfr_[n2][0], acc[(mh_)*4 + m2][(nh_)*2 + n2], 0, 0, 0);      \
        acc[(mh_)*4 + m2][(nh_)*2 + n2] = __builtin_amdgcn_mfma_f32_16x16x32_bf16( \
            A[m2][1], bfr_[n2][1], acc[(mh_)*4 + m2][(nh_)*2 + n2], 0, 0, 0);      \
      } }                                                                    \
    __builtin_amdgcn_s_setprio(0);                                           \
  } while (0)

// One K-tile. buf_ MUST be literal 0/1. SB_/SA_ compile-time guards;
// VM_ is the vmcnt statement at Ph0 (after staging, before BAR).
#define KTILE(buf_, g_, SB_, SA_, VM_) do {                                  \
    /* Ph0 */                                                                \
    if (SB_) STAGE_B((buf_) ^ 1, (g_) + 1);                                  \
    VM_;                                                                     \
    BAR;                                                                     \
    RD_A(buf_, 0);                                                           \
    RD_B(buf_, 0, B0);                                                       \
    RD_B(buf_, 1, B1);                                                       \
    MM16(B0, 0, 0);                                                          \
    MM16(B1, 0, 1);                                                          \
    /* Ph1 */                                                                \
    if (SA_) STAGE_A((buf_) ^ 1, (g_) + 1);                                  \
    BAR;                                                                     \
    RD_A(buf_, 1);                                                           \
    MM16(B0, 1, 0);                                                          \
    MM16(B1, 1, 1);                                                          \
  } while (0)

__global__ __launch_bounds__(512, 2) void gemm8_kernel(const unsigned short* __restrict__ xbf,
                                                       const unsigned short* __restrict__ weff,
                                                       const float* __restrict__ bias,
                                                       float* __restrict__ out) {
  __shared__ __attribute__((aligned(1024))) char lds[2][4][16384];  // 128 KiB

  const int tid  = threadIdx.x;
  const int lane = tid & 63;
  const int wid  = tid >> 6;
  const int wr   = wid >> 2;        // 0..1  (M half)
  const int wc   = wid & 3;         // 0..3  (N quarter)

  // bijective XCD swizzle: 1024 wgs, 8 XCDs -> each XCD gets 8 M-rows x 16 N-cols
  const int id  = blockIdx.x;
  const int nid = (id & 7) * 128 + (id >> 3);
  const int tn  = nid & 15;         // N tile (16)
  const int tm  = nid >> 4;         // M tile (64)

  // ds_read lane offsets (swizzled): addr = row*128 + ((kk*64 + (l>>4)*16) ^ ((l&7)<<4))
  const int rowb  = (lane & 15) * 128;
  const int kx    = (lane & 7) << 4;
  const int koff0 = (((lane >> 4) * 16) ^ kx);
  const int koff1 = ((64 + (lane >> 4) * 16) ^ kx);

  // staging lane offsets (inverse-swizzled source)
  const int sr = tid >> 3;                        // row within 64-row chunk
  const int ke = ((tid & 7) ^ (sr & 7)) * 8;      // permuted k-element offset
  const unsigned short* gA = xbf  + (size_t)(tm * BM + sr) * D_IN + ke;
  const unsigned short* gB = weff + (size_t)(tn * BN + sr) * D_IN + ke;

  f32x4 acc[8][4] = {};
  bf16x8 A[4][2], B0[2][2], B1[2][2];

  // prologue: tile 0 A+B -> buf0 (8 loads). Tile-0 Ph0's vmcnt(4)+BAR does the
  // drain: queue there = A(0)x4, B(0)x4, B(1)x4 -> drains tile 0, keeps B(1).
  STAGE_A(0, 0);
  STAGE_B(0, 0);

  for (int g = 0; g < KT - 2; g += 2) {
    KTILE(0, g,     1, 1, VMW(4));
    KTILE(1, g + 1, 1, 1, VMW(4));
  }
  // tile KT-2 (buf0): stages B(KT-1), A(KT-1) normally
  KTILE(0, KT - 2, 1, 1, VMW(4));
  // tile KT-1 (buf1): no staging; full drain at Ph0
  KTILE(1, KT - 1, 0, 0, VMW(0));

  // epilogue: C/D layout col = lane&15, row = (lane>>4)*4 + j  [m89-verified]
  const int row0 = tm * BM + wr * 128 + (lane >> 4) * 4;
  const int col0 = tn * BN + wc * 64 + (lane & 15);
#pragma unroll
  for (int n = 0; n < 4; ++n) {
    const int col = col0 + n * 16;
    const float bv = bias[col];
#pragma unroll
    for (int m = 0; m < 8; ++m) {
      const int r = row0 + m * 16;
#pragma unroll
      for (int j = 0; j < 4; ++j)
        out[(size_t)(r + j) * D_OUT + col] = acc[m][n][j] + bv;
    }
  }
}

extern "C" void kernel_launch(void* const* d_in, const int* in_sizes, int n_in,
                              void* d_out, int out_size, void* d_ws, size_t ws_size,
                              hipStream_t stream) {
  const float* x      = (const float*)d_in[0];
  const int*   codes  = (const int*)d_in[1];
  const float* scales = (const float*)d_in[2];
  const float* bias   = (const float*)d_in[3];
  const float* delta  = (const float*)d_in[4];
  float* out = (float*)d_out;

  unsigned short* xbf  = (unsigned short*)d_ws;                    // 128 MiB
  unsigned short* weff = xbf + (size_t)MTOT * D_IN;                // +32 MiB

  prep_x_kernel<<<(MTOT * D_IN) / (256 * 8), 256, 0, stream>>>(x, xbf);
  prep_w_kernel<<<(D_OUT * D_IN) / (256 * 8), 256, 0, stream>>>(codes, scales, delta, weff);

  gemm8_kernel<<<(MTOT / BM) * (D_OUT / BN), 512, 0, stream>>>(xbf, weff, bias, out);
}

// Round 14
// 553.892 us; speedup vs baseline: 1.0416x; 1.0416x over previous
//
#include <hip/hip_runtime.h>
#include <cstdint>

// Problem geometry (fixed by the reference)
#define D_IN   4096
#define D_OUT  4096
#define MTOT   16384      // B*S = 8*2048
#define SCALING 2.0f

// GEMM tiling: 256x256 tile, BK=64, 8 waves (2M x 4N), 4 single-barrier phases
#define BM 256
#define BN 256
#define BK 64
#define KT (D_IN / BK)    // 64 K-tiles

#define XBLOCKS ((MTOT * D_IN) / (256 * 8))   // 32768 prep blocks for x
#define WBLOCKS ((D_OUT * D_IN) / (256 * 8))  // 8192 prep blocks for w

typedef float  f32x4  __attribute__((ext_vector_type(4)));
typedef __bf16 bf16x8 __attribute__((ext_vector_type(8)));
typedef unsigned short ushort8 __attribute__((ext_vector_type(8)));
typedef int    int4v  __attribute__((ext_vector_type(4)));
typedef float  float4v __attribute__((ext_vector_type(4)));

// round-to-nearest-even f32 -> bf16
__device__ __forceinline__ unsigned short f2bf(float f) {
  union { float f; unsigned u; } v; v.f = f;
  unsigned r = v.u + 0x7FFF + ((v.u >> 16) & 1);
  return (unsigned short)(r >> 16);
}

// async global->LDS, 16B per lane (wave-uniform base + lane*16 on LDS side)
#define ASYNC16(g, l)                                                        \
  __builtin_amdgcn_global_load_lds(                                          \
      (const __attribute__((address_space(1))) unsigned int*)(g),            \
      (__attribute__((address_space(3))) unsigned int*)(l), 16, 0, 0)

#define BAR    __builtin_amdgcn_s_barrier()
#define VMW(n) asm volatile("s_waitcnt vmcnt(" #n ")" ::: "memory")

// ---------------------------------------------------- fused prep (one launch):
// blocks [0, XBLOCKS):          x f32 -> bf16
// blocks [XBLOCKS, +WBLOCKS):   W_eff = (codes-8)*scale + 2*delta -> bf16
__global__ __launch_bounds__(256) void prep_kernel(const float* __restrict__ x,
                                                   unsigned short* __restrict__ xbf,
                                                   const int* __restrict__ codes,
                                                   const float* __restrict__ scales,
                                                   const float* __restrict__ delta,
                                                   unsigned short* __restrict__ weff) {
  const int bid = blockIdx.x;
  if (bid < XBLOCKS) {
    int i = (bid * 256 + threadIdx.x) * 8;
    float4v lo = *(const float4v*)(x + i);
    float4v hi = *(const float4v*)(x + i + 4);
    ushort8 o;
    o[0] = f2bf(lo[0]); o[1] = f2bf(lo[1]); o[2] = f2bf(lo[2]); o[3] = f2bf(lo[3]);
    o[4] = f2bf(hi[0]); o[5] = f2bf(hi[1]); o[6] = f2bf(hi[2]); o[7] = f2bf(hi[3]);
    *(ushort8*)(xbf + i) = o;
  } else {
    int i = ((bid - XBLOCKS) * 256 + threadIdx.x) * 8;  // 8 elems, same group
    int row = i >> 12;          // / D_IN
    int col = i & (D_IN - 1);
    float s = scales[(row << 6) + (col >> 6)];          // 64 groups per row
    int4v   c0 = *(const int4v*)(codes + i);
    int4v   c1 = *(const int4v*)(codes + i + 4);
    float4v d0 = *(const float4v*)(delta + i);
    float4v d1 = *(const float4v*)(delta + i + 4);
    ushort8 o;
    o[0] = f2bf((float)(c0[0] - 8) * s + SCALING * d0[0]);
    o[1] = f2bf((float)(c0[1] - 8) * s + SCALING * d0[1]);
    o[2] = f2bf((float)(c0[2] - 8) * s + SCALING * d0[2]);
    o[3] = f2bf((float)(c0[3] - 8) * s + SCALING * d0[3]);
    o[4] = f2bf((float)(c1[0] - 8) * s + SCALING * d1[0]);
    o[5] = f2bf((float)(c1[1] - 8) * s + SCALING * d1[1]);
    o[6] = f2bf((float)(c1[2] - 8) * s + SCALING * d1[2]);
    o[7] = f2bf((float)(c1[3] - 8) * s + SCALING * d1[3]);
    *(ushort8*)(weff + i) = o;
  }
}

// ---------------------------------------------------------------- main GEMM
// C[M][N] = Xbf[M][K] * Weff[N][K]^T + bias
// r12 best-known structure (4 single-barrier phases, 463 us, MfmaUtil 54.6%):
//   P0: stage A(g+1)h0 | BAR | rd A0(8)+B0(4), MM16(A0,B0)
//   P1: stage A(g+1)h1 | BAR | rd B1(4),       MM16(A0,B1)
//   P2: stage B(g+2)h0 | BAR | rd A1(8),       MM16(A1,B0)
//   P3: stage B(g+2)h1 | BAR |                 MM16(A1,B1) | vmcnt(4)
// Single-barrier WAR audit (waves at most ONE phase apart; a STAGE at
// phase-top only races phase p-1 readers):
//   P0 stages buf^1.A0 : P3 reads nothing            -> safe
//   P1 stages buf^1.A1 : P0 reads buf slots only     -> safe
//   P2 stages buf.B0   : P1 reads buf.B1 only        -> safe
//   P3 stages buf.B1   : P2 reads buf.A1 only        -> safe
// Each wave's ds_reads are lgkm-drained by its own MM16 before it reaches the
// next barrier. Whole-tile drain (round-8 lesson: all 4 slots are read at P0
// by wave-dependent slot selects): vmcnt(4) at tile end, queue = B(g+1)x4,
// A(g+1)x4, B(g+2)x4 = 12 -> drains tile g+1 fully, leaves B(g+2) (never 0).
// LDS slots/buf: [A0 rows0-127][A1][B0][B1], each [128][64] bf16, XOR-swizzled
// byte ^= ((row&7)<<4): inverse-swizzled global source + swizzled ds_read.
// Loop unrolled x2 so buf is a LITERAL (immediate-offset folding).

#define STAGE_A(buf_, kt_, h_) do {                                          \
    char* d_ = &lds[buf_][h_][0] + tid * 16;                                 \
    const unsigned short* s_ = gA + (size_t)(h_) * 128 * D_IN + (kt_) * 64;  \
    ASYNC16(s_, d_);                                                         \
    ASYNC16(s_ + 64 * D_IN, d_ + 8192);                                      \
  } while (0)

#define STAGE_B(buf_, kt_, h_) do {                                          \
    char* d_ = &lds[buf_][2 + (h_)][0] + tid * 16;                           \
    const unsigned short* s_ = gB + (size_t)(h_) * 128 * D_IN + (kt_) * 64;  \
    ASYNC16(s_, d_);                                                         \
    ASYNC16(s_ + 64 * D_IN, d_ + 8192);                                      \
  } while (0)

// read A-half h_ (4 m-frags, rows h*64..h*64+63 of wave's panel) -> A[4][2]
#define RD_A(buf_, h_) do {                                                  \
    _Pragma("unroll")                                                        \
    for (int m2 = 0; m2 < 4; ++m2) {                                         \
      const char* p_ = &lds[buf_][wr][0] + ((h_)*4 + m2) * 2048 + rowb;      \
      A[m2][0] = *(const bf16x8*)(p_ + koff0);                               \
      A[m2][1] = *(const bf16x8*)(p_ + koff1);                               \
    } } while (0)

// read B-half h_ (2 n-frags) of the wave's 64-col B panel
#define RD_B(buf_, h_, dst_) do {                                            \
    _Pragma("unroll")                                                        \
    for (int n2 = 0; n2 < 2; ++n2) {                                         \
      const char* p_ = &lds[buf_][2 + (wc >> 1)][0] + (wc & 1) * 8192 +      \
                       (h_) * 4096 + n2 * 2048 + rowb;                       \
      dst_[n2][0] = *(const bf16x8*)(p_ + koff0);                            \
      dst_[n2][1] = *(const bf16x8*)(p_ + koff1);                            \
    } } while (0)

// 16 MFMA: A-half (acc rows mh*4..+3) x B-half (acc cols nh*2..+1), K=64
#define MM16(bfr_, mh_, nh_) do {                                            \
    __builtin_amdgcn_s_setprio(1);                                           \
    _Pragma("unroll")                                                        \
    for (int m2 = 0; m2 < 4; ++m2) {                                         \
      _Pragma("unroll")                                                      \
      for (int n2 = 0; n2 < 2; ++n2) {                                       \
        acc[(mh_)*4 + m2][(nh_)*2 + n2] = __builtin_amdgcn_mfma_f32_16x16x32_bf16( \
            A[m2][0], bfr_[n2][0], acc[(mh_)*4 + m2][(nh_)*2 + n2], 0, 0, 0);      \
        acc[(mh_)*4 + m2][(nh_)*2 + n2] = __builtin_amdgcn_mfma_f32_16x16x32_bf16( \
            A[m2][1], bfr_[n2][1], acc[(mh_)*4 + m2][(nh_)*2 + n2], 0, 0, 0);      \
      } }                                                                    \
    __builtin_amdgcn_s_setprio(0);                                           \
  } while (0)

// One K-tile. buf_ MUST be literal 0/1. SA_/SB_ compile-time guards;
// VM_ is the vmcnt statement at tile end (after MM_P3).
#define KTILE(buf_, g_, SA_, SB_, VM_) do {                                  \
    /* P0 */                                                                 \
    if (SA_) STAGE_A((buf_) ^ 1, (g_) + 1, 0);                               \
    BAR;                                                                     \
    RD_A(buf_, 0);                                                           \
    RD_B(buf_, 0, B0);                                                       \
    MM16(B0, 0, 0);                                                          \
    /* P1 */                                                                 \
    if (SA_) STAGE_A((buf_) ^ 1, (g_) + 1, 1);                               \
    BAR;                                                                     \
    RD_B(buf_, 1, B1);                                                       \
    MM16(B1, 0, 1);                                                          \
    /* P2 */                                                                 \
    if (SB_) STAGE_B(buf_, (g_) + 2, 0);                                     \
    BAR;                                                                     \
    RD_A(buf_, 1);                                                           \
    MM16(B0, 1, 0);                                                          \
    /* P3 */                                                                 \
    if (SB_) STAGE_B(buf_, (g_) + 2, 1);                                     \
    BAR;                                                                     \
    MM16(B1, 1, 1);                                                          \
    VM_;                                                                     \
  } while (0)

__global__ __launch_bounds__(512, 2) void gemm8_kernel(const unsigned short* __restrict__ xbf,
                                                       const unsigned short* __restrict__ weff,
                                                       const float* __restrict__ bias,
                                                       float* __restrict__ out) {
  __shared__ __attribute__((aligned(1024))) char lds[2][4][16384];  // 128 KiB

  const int tid  = threadIdx.x;
  const int lane = tid & 63;
  const int wid  = tid >> 6;
  const int wr   = wid >> 2;        // 0..1  (M half)
  const int wc   = wid & 3;         // 0..3  (N quarter)

  // bijective XCD swizzle: 1024 wgs, 8 XCDs -> each XCD gets 8 M-rows x 16 N-cols
  const int id  = blockIdx.x;
  const int nid = (id & 7) * 128 + (id >> 3);
  const int tn  = nid & 15;         // N tile (16)
  const int tm  = nid >> 4;         // M tile (64)

  // ds_read lane offsets (swizzled): addr = row*128 + ((kk*64 + (l>>4)*16) ^ ((l&7)<<4))
  const int rowb  = (lane & 15) * 128;
  const int kx    = (lane & 7) << 4;
  const int koff0 = (((lane >> 4) * 16) ^ kx);
  const int koff1 = ((64 + (lane >> 4) * 16) ^ kx);

  // staging lane offsets (inverse-swizzled source)
  const int sr = tid >> 3;                        // row within 64-row chunk
  const int ke = ((tid & 7) ^ (sr & 7)) * 8;      // permuted k-element offset
  const unsigned short* gA = xbf  + (size_t)(tm * BM + sr) * D_IN + ke;
  const unsigned short* gB = weff + (size_t)(tn * BN + sr) * D_IN + ke;

  f32x4 acc[8][4] = {};
  bf16x8 A[4][2], B0[2][2], B1[2][2];

  // prologue: tile 0 (A+B) -> buf0 ; B of tile 1 -> buf1  (12 loads)
  STAGE_A(0, 0, 0); STAGE_A(0, 0, 1);
  STAGE_B(0, 0, 0); STAGE_B(0, 0, 1);
  STAGE_B(1, 1, 0); STAGE_B(1, 1, 1);
  VMW(4);           // tile 0 fully landed; B(1)x4 stays in flight
                    // (tile 0's P0 barrier is the release point for all waves)

  for (int g = 0; g < KT - 2; g += 2) {
    KTILE(0, g,     1, 1, VMW(4));
    KTILE(1, g + 1, 1, 1, VMW(4));
  }
  // tile KT-2 (buf0): stages A(KT-1) only; end queue = B(KT-1)x4 + A(KT-1)x4
  //   -> full drain so tile KT-1 is complete before its P0 reads.
  KTILE(0, KT - 2, 1, 0, VMW(0));
  // tile KT-1 (buf1): pure compute
  KTILE(1, KT - 1, 0, 0, (void)0);

  // epilogue: C/D layout col = lane&15, row = (lane>>4)*4 + j  [m89-verified]
  const int row0 = tm * BM + wr * 128 + (lane >> 4) * 4;
  const int col0 = tn * BN + wc * 64 + (lane & 15);
#pragma unroll
  for (int n = 0; n < 4; ++n) {
    const int col = col0 + n * 16;
    const float bv = bias[col];
#pragma unroll
    for (int m = 0; m < 8; ++m) {
      const int r = row0 + m * 16;
#pragma unroll
      for (int j = 0; j < 4; ++j)
        out[(size_t)(r + j) * D_OUT + col] = acc[m][n][j] + bv;
    }
  }
}

extern "C" void kernel_launch(void* const* d_in, const int* in_sizes, int n_in,
                              void* d_out, int out_size, void* d_ws, size_t ws_size,
                              hipStream_t stream) {
  const float* x      = (const float*)d_in[0];
  const int*   codes  = (const int*)d_in[1];
  const float* scales = (const float*)d_in[2];
  const float* bias   = (const float*)d_in[3];
  const float* delta  = (const float*)d_in[4];
  float* out = (float*)d_out;

  unsigned short* xbf  = (unsigned short*)d_ws;                    // 128 MiB
  unsigned short* weff = xbf + (size_t)MTOT * D_IN;                // +32 MiB

  prep_kernel<<<XBLOCKS + WBLOCKS, 256, 0, stream>>>(x, xbf, codes, scales, delta, weff);

  gemm8_kernel<<<(MTOT / BM) * (D_OUT / BN), 512, 0, stream>>>(xbf, weff, bias, out);
}